// Round 1
// baseline (2831.073 us; speedup 1.0000x reference)
//
#include <hip/hip_runtime.h>
#include <math.h>

// Problem constants (from reference)
#define NN 50000        // nodes
#define NE 800000       // edges
#define DIN 256
#define DOUT 768

// ---------------------------------------------------------------------------
// Degree / CSR construction
// ---------------------------------------------------------------------------
__global__ void init_deg_cnt(float* __restrict__ deg, int* __restrict__ cnt) {
    int i = blockIdx.x * 256 + threadIdx.x;
    if (i < NN) { deg[i] = 1.0f; cnt[i] = 0; }   // self-loop weight 1 pre-added
}

__global__ void edge_deg_cnt(const int* __restrict__ ei, const float* __restrict__ ea,
                             float* __restrict__ deg, int* __restrict__ cnt) {
    int e = blockIdx.x * 256 + threadIdx.x;
    if (e >= NE) return;
    int dst = ei[NE + e];
    atomicAdd(&deg[dst], ea[e]);
    atomicAdd(&cnt[dst], 1);
}

__global__ void compute_dinv(const float* __restrict__ deg, float* __restrict__ dinv) {
    int i = blockIdx.x * 256 + threadIdx.x;
    if (i < NN) { float d = deg[i]; dinv[i] = d > 0.f ? rsqrtf(d) : 0.f; }
}

// single-block exclusive scan of cnt -> row_ptr (and cursor copy)
__global__ void scan_kernel(const int* __restrict__ cnt, int* __restrict__ row_ptr,
                            int* __restrict__ cursor) {
    __shared__ int ssum[256];
    int t = threadIdx.x;
    const int chunk = (NN + 255) / 256;   // 196
    int beg = t * chunk;
    int end = beg + chunk; if (end > NN) end = NN;
    int s = 0;
    for (int i = beg; i < end; ++i) s += cnt[i];
    ssum[t] = s;
    __syncthreads();
    if (t == 0) {
        int run = 0;
        for (int i = 0; i < 256; ++i) { int v = ssum[i]; ssum[i] = run; run += v; }
    }
    __syncthreads();
    int run = ssum[t];
    for (int i = beg; i < end; ++i) {
        row_ptr[i] = run; cursor[i] = run; run += cnt[i];
    }
    if (t == 255) row_ptr[NN] = run;   // == NE
}

__global__ void edge_scatter(const int* __restrict__ ei, const float* __restrict__ ea,
                             const float* __restrict__ dinv, int* __restrict__ cursor,
                             int* __restrict__ col, float* __restrict__ val) {
    int e = blockIdx.x * 256 + threadIdx.x;
    if (e >= NE) return;
    int s = ei[e];
    int d = ei[NE + e];
    int pos = atomicAdd(&cursor[d], 1);
    col[pos] = s;
    val[pos] = dinv[s] * ea[e] * dinv[d];
}

// ---------------------------------------------------------------------------
// Aggregation: Gout[i,:] = sum_{e: dst=i} val_e * Gin[col_e,:] + dinv[i]^2 * Gin[i,:]
// Also propagates the "ones" vector R (Rin==nullptr means all-ones input).
// One block (256 threads) per node; thread t owns feature dim t.
// ---------------------------------------------------------------------------
__global__ __launch_bounds__(256) void agg_kernel(
        const float* __restrict__ Gin, int in_stride,
        float* __restrict__ Gout, int out_stride,
        const float* __restrict__ Rin, float* __restrict__ Rout,
        const int* __restrict__ row_ptr, const int* __restrict__ col,
        const float* __restrict__ val, const float* __restrict__ dinv) {
    int node = blockIdx.x;
    int t = threadIdx.x;
    int beg = row_ptr[node], end = row_ptr[node + 1];
    float acc = 0.f;
    float racc = 0.f;
    for (int k = beg; k < end; ++k) {
        int c = col[k];
        float v = val[k];
        acc += v * Gin[(size_t)c * in_stride + t];
        if (t == 0) racc += v * (Rin ? Rin[c] : 1.0f);
    }
    float dv = dinv[node];
    float sv = dv * dv;
    acc += sv * Gin[(size_t)node * in_stride + t];
    Gout[(size_t)node * out_stride + t] = acc;
    if (t == 0) {
        racc += sv * (Rin ? Rin[node] : 1.0f);
        Rout[node] = racc;
    }
}

// ---------------------------------------------------------------------------
// Small dense helpers (weight-side precompute; tiny, simplicity > speed)
// ---------------------------------------------------------------------------
__global__ void sgemm_small(const float* __restrict__ A, const float* __restrict__ B,
                            float* __restrict__ C, int M, int N, int K) {
    int idx = blockIdx.x * blockDim.x + threadIdx.x;
    if (idx >= M * N) return;
    int i = idx / N, j = idx - i * N;
    float s = 0.f;
    for (int k = 0; k < K; ++k) s += A[i * K + k] * B[(size_t)k * N + j];
    C[idx] = s;
}

__global__ void vecmat(const float* __restrict__ v, const float* __restrict__ B,
                       float* __restrict__ out, int K, int N, int ldb, int accum) {
    int j = blockIdx.x * blockDim.x + threadIdx.x;
    if (j >= N) return;
    float s = 0.f;
    for (int k = 0; k < K; ++k) s += v[k] * B[(size_t)k * ldb + j];
    if (accum) out[j] += s; else out[j] = s;
}

__global__ void vadd(float* __restrict__ out, const float* __restrict__ b, int N) {
    int j = blockIdx.x * blockDim.x + threadIdx.x;
    if (j < N) out[j] += b[j];
}

// ---------------------------------------------------------------------------
// Main GEMM: C[M,768] = A[M,768] @ B[768,768]  + rank-1 epilogue
//   C[i,j] += c0[j] + R1[i]*u1[j] + R2[i]*u2[j] + R3[i]*u3[j]
// 128x128 block tile, 8x8 per thread, TK=16, fp32 vector ALU.
// ---------------------------------------------------------------------------
#define TM 128
#define TN 128
#define TKK 16

__global__ __launch_bounds__(256) void gemm_main(
        const float* __restrict__ A, const float* __restrict__ B,
        float* __restrict__ C, int M,
        const float* __restrict__ R1, const float* __restrict__ R2,
        const float* __restrict__ R3,
        const float* __restrict__ u1, const float* __restrict__ u2,
        const float* __restrict__ u3, const float* __restrict__ c0) {
    __shared__ float As[TKK][TM + 4];
    __shared__ float Bs[TKK][TN + 4];
    const int tid = threadIdx.x;
    const int bm = blockIdx.y * TM;
    const int bn = blockIdx.x * TN;
    const int tx = tid & 15;
    const int ty = tid >> 4;
    float acc[8][8];
#pragma unroll
    for (int i = 0; i < 8; ++i)
#pragma unroll
        for (int j = 0; j < 8; ++j) acc[i][j] = 0.f;

    for (int k0 = 0; k0 < DOUT; k0 += TKK) {
        // A tile: 128 rows x 16 k, float4 along k, stored transposed
#pragma unroll
        for (int l = 0; l < 2; ++l) {
            int lin = tid + l * 256;          // 0..511
            int row = lin >> 2;               // 0..127
            int kc = (lin & 3) * 4;           // 0,4,8,12
            int gr = bm + row;
            float4 av;
            if (gr < M) av = *(const float4*)(A + (size_t)gr * DOUT + k0 + kc);
            else av = make_float4(0.f, 0.f, 0.f, 0.f);
            As[kc + 0][row] = av.x; As[kc + 1][row] = av.y;
            As[kc + 2][row] = av.z; As[kc + 3][row] = av.w;
        }
        // B tile: 16 k x 128 cols
#pragma unroll
        for (int l = 0; l < 2; ++l) {
            int lin = tid + l * 256;
            int row = lin >> 5;               // 0..15
            int nc = (lin & 31) * 4;          // 0..124
            float4 bv = *(const float4*)(B + (size_t)(k0 + row) * DOUT + bn + nc);
            *(float4*)(&Bs[row][nc]) = bv;
        }
        __syncthreads();
#pragma unroll
        for (int k = 0; k < TKK; ++k) {
            float a[8], b[8];
            *(float4*)&a[0] = *(const float4*)&As[k][ty * 8];
            *(float4*)&a[4] = *(const float4*)&As[k][ty * 8 + 4];
            *(float4*)&b[0] = *(const float4*)&Bs[k][tx * 8];
            *(float4*)&b[4] = *(const float4*)&Bs[k][tx * 8 + 4];
#pragma unroll
            for (int i = 0; i < 8; ++i)
#pragma unroll
                for (int j = 0; j < 8; ++j) acc[i][j] += a[i] * b[j];
        }
        __syncthreads();
    }
    // epilogue: constant + rank-1 bias terms
#pragma unroll
    for (int i = 0; i < 8; ++i) {
        int gr = bm + ty * 8 + i;
        if (gr >= M) continue;
        float r1 = R1[gr], r2 = R2[gr], r3 = R3[gr];
#pragma unroll
        for (int j = 0; j < 8; ++j) {
            int gc = bn + tx * 8 + j;
            float v = acc[i][j] + c0[gc] + r1 * u1[gc] + r2 * u2[gc] + r3 * u3[gc];
            C[(size_t)gr * DOUT + gc] = v;
        }
    }
}

// ---------------------------------------------------------------------------
// Fused LayerNorm + exact GELU, in-place. One block per row.
// ---------------------------------------------------------------------------
__global__ __launch_bounds__(256) void ln_gelu_kernel(float* __restrict__ out,
        const float* __restrict__ gamma, const float* __restrict__ beta) {
    int row = blockIdx.x;
    int t = threadIdx.x;
    float* p = out + (size_t)row * DOUT;
    float x0 = p[t], x1 = p[t + 256], x2 = p[t + 512];
    float s = x0 + x1 + x2;
    float s2 = x0 * x0 + x1 * x1 + x2 * x2;
    __shared__ float red[8];
    int wave = t >> 6, lane = t & 63;
#pragma unroll
    for (int m = 1; m < 64; m <<= 1) {
        s += __shfl_xor(s, m);
        s2 += __shfl_xor(s2, m);
    }
    if (lane == 0) { red[wave] = s; red[4 + wave] = s2; }
    __syncthreads();
    float S = red[0] + red[1] + red[2] + red[3];
    float S2 = red[4] + red[5] + red[6] + red[7];
    float mu = S * (1.f / 768.f);
    float var = S2 * (1.f / 768.f) - mu * mu;
    float inv = rsqrtf(var + 1e-5f);
    const float k = 0.70710678118654752f;
#pragma unroll
    for (int i = 0; i < 3; ++i) {
        int c = t + 256 * i;
        float x = (i == 0) ? x0 : (i == 1) ? x1 : x2;
        float y = (x - mu) * inv * gamma[c] + beta[c];
        p[c] = 0.5f * y * (1.f + erff(y * k));
    }
}

// ---------------------------------------------------------------------------
// Launch
// ---------------------------------------------------------------------------
extern "C" void kernel_launch(void* const* d_in, const int* in_sizes, int n_in,
                              void* d_out, int out_size, void* d_ws, size_t ws_size,
                              hipStream_t stream) {
    const float* x     = (const float*)d_in[0];
    const int*   ei    = (const int*)d_in[1];     // [2, NE] (JAX default int32)
    const float* ea    = (const float*)d_in[2];   // [NE, 1]
    const float* W1    = (const float*)d_in[3];
    const float* b1    = (const float*)d_in[4];
    const float* W2    = (const float*)d_in[5];
    const float* b2    = (const float*)d_in[6];
    const float* W3    = (const float*)d_in[7];
    const float* b3    = (const float*)d_in[8];
    const float* Wp    = (const float*)d_in[9];   // [768,768]
    const float* bp    = (const float*)d_in[10];
    const float* gamma = (const float*)d_in[11];
    const float* beta  = (const float*)d_in[12];
    float* out = (float*)d_out;

    // workspace bump allocator (total ~216 MB)
    char* w = (char*)d_ws;
    auto alloc = [&](size_t bytes) -> void* {
        void* p = (void*)w;
        w += (bytes + 255) & ~(size_t)255;
        return p;
    };
    float* Gcat   = (float*)alloc((size_t)NN * DOUT * 4);  // G1|G2|G4 columns
    float* G3t    = (float*)alloc((size_t)NN * DIN * 4);
    int*   col    = (int*)alloc((size_t)NE * 4);
    float* val    = (float*)alloc((size_t)NE * 4);
    float* deg    = (float*)alloc((size_t)NN * 4);
    float* dinv   = (float*)alloc((size_t)NN * 4);
    int*   cnt    = (int*)alloc((size_t)NN * 4);
    int*   rowp   = (int*)alloc((size_t)(NN + 1) * 4);
    int*   cursor = (int*)alloc((size_t)NN * 4);
    float* R1     = (float*)alloc((size_t)NN * 4);
    float* R2     = (float*)alloc((size_t)NN * 4);
    float* R3     = (float*)alloc((size_t)NN * 4);
    float* R4     = (float*)alloc((size_t)NN * 4);
    float* W2sq   = (float*)alloc(256 * 256 * 4);
    float* W3_2   = (float*)alloc(256 * 256 * 4);
    float* W3_4   = (float*)alloc(256 * 256 * 4);
    float* Mcat   = (float*)alloc(768 * 768 * 4);
    float* bw2    = (float*)alloc(256 * 4);
    float* bw3a   = (float*)alloc(256 * 4);
    float* bw3b   = (float*)alloc(256 * 4);
    float* bw3c   = (float*)alloc(256 * 4);
    float* u1     = (float*)alloc(768 * 4);
    float* u2     = (float*)alloc(768 * 4);
    float* u3     = (float*)alloc(768 * 4);
    float* c0     = (float*)alloc(768 * 4);

    const int nb_n = (NN + 255) / 256;
    const int nb_e = (NE + 255) / 256;

    // degree + CSR
    init_deg_cnt<<<nb_n, 256, 0, stream>>>(deg, cnt);
    edge_deg_cnt<<<nb_e, 256, 0, stream>>>(ei, ea, deg, cnt);
    compute_dinv<<<nb_n, 256, 0, stream>>>(deg, dinv);
    scan_kernel<<<1, 256, 0, stream>>>(cnt, rowp, cursor);
    edge_scatter<<<nb_e, 256, 0, stream>>>(ei, ea, dinv, cursor, col, val);

    // weight-side precompute:
    //   Mcat rows 0-255  = W1   @ Wp[0:256]
    //   Mcat rows 256-511= W2^2 @ Wp[256:512]
    //   Mcat rows 512-767= W3^4 @ Wp[512:768]
    sgemm_small<<<(256 * 256 + 255) / 256, 256, 0, stream>>>(W2, W2, W2sq, 256, 256, 256);
    sgemm_small<<<(256 * 256 + 255) / 256, 256, 0, stream>>>(W3, W3, W3_2, 256, 256, 256);
    sgemm_small<<<(256 * 256 + 255) / 256, 256, 0, stream>>>(W3_2, W3_2, W3_4, 256, 256, 256);
    sgemm_small<<<(256 * 768 + 255) / 256, 256, 0, stream>>>(W1, Wp, Mcat, 256, 768, 256);
    sgemm_small<<<(256 * 768 + 255) / 256, 256, 0, stream>>>(W2sq, Wp + 256 * 768, Mcat + 256 * 768, 256, 768, 256);
    sgemm_small<<<(256 * 768 + 255) / 256, 256, 0, stream>>>(W3_4, Wp + 512 * 768, Mcat + 512 * 768, 256, 768, 256);
    // bias vectors: b W^k
    vecmat<<<1, 256, 0, stream>>>(b2, W2, bw2, 256, 256, 256, 0);
    vecmat<<<1, 256, 0, stream>>>(b3, W3, bw3a, 256, 256, 256, 0);
    vecmat<<<1, 256, 0, stream>>>(bw3a, W3, bw3b, 256, 256, 256, 0);
    vecmat<<<1, 256, 0, stream>>>(bw3b, W3, bw3c, 256, 256, 256, 0);
    // u1 = bw2@P2 + bw3a@P3 ; u2 = bw3b@P3 ; u3 = bw3c@P3
    vecmat<<<3, 256, 0, stream>>>(bw2, Wp + 256 * 768, u1, 256, 768, 768, 0);
    vecmat<<<3, 256, 0, stream>>>(bw3a, Wp + 512 * 768, u1, 256, 768, 768, 1);
    vecmat<<<3, 256, 0, stream>>>(bw3b, Wp + 512 * 768, u2, 256, 768, 768, 0);
    vecmat<<<3, 256, 0, stream>>>(bw3c, Wp + 512 * 768, u3, 256, 768, 768, 0);
    // c0 = b1@P1 + b2@P2 + b3@P3 + bp
    vecmat<<<3, 256, 0, stream>>>(b1, Wp, c0, 256, 768, 768, 0);
    vecmat<<<3, 256, 0, stream>>>(b2, Wp + 256 * 768, c0, 256, 768, 768, 1);
    vecmat<<<3, 256, 0, stream>>>(b3, Wp + 512 * 768, c0, 256, 768, 768, 1);
    vadd<<<3, 256, 0, stream>>>(c0, bp, 768);

    // shared aggregation chain: G1=Ax, G2=A G1, G3=A G2, G4=A G3 (+ R chain)
    agg_kernel<<<NN, 256, 0, stream>>>(x, DIN, Gcat, DOUT, nullptr, R1, rowp, col, val, dinv);
    agg_kernel<<<NN, 256, 0, stream>>>(Gcat, DOUT, Gcat + 256, DOUT, R1, R2, rowp, col, val, dinv);
    agg_kernel<<<NN, 256, 0, stream>>>(Gcat + 256, DOUT, G3t, DIN, R2, R3, rowp, col, val, dinv);
    agg_kernel<<<NN, 256, 0, stream>>>(G3t, DIN, Gcat + 512, DOUT, R3, R4, rowp, col, val, dinv);

    // fused projection GEMM + bias epilogue
    dim3 grid(DOUT / TN, (NN + TM - 1) / TM);
    gemm_main<<<grid, 256, 0, stream>>>(Gcat, Mcat, out, NN, R1, R2, R3, u1, u2, u3, c0);

    // LayerNorm + exact GELU in-place
    ln_gelu_kernel<<<NN, 256, 0, stream>>>(out, gamma, beta);
}

// Round 2
// 2069.859 us; speedup vs baseline: 1.3678x; 1.3678x over previous
//
#include <hip/hip_runtime.h>
#include <math.h>

#define NN 50000        // nodes
#define NE 800000       // edges
#define DIN 256
#define DOUT 768
#define NPAD 50176      // NN padded to multiple of 128 for GEMM tile staging

typedef __bf16 bf16x8 __attribute__((ext_vector_type(8)));
typedef __bf16 bf16x4 __attribute__((ext_vector_type(4)));
typedef float  f32x4  __attribute__((ext_vector_type(4)));

// ---------------------------------------------------------------------------
// Degree / CSR construction
// ---------------------------------------------------------------------------
__global__ void init_deg_cnt(float* __restrict__ deg, int* __restrict__ cnt) {
    int i = blockIdx.x * 256 + threadIdx.x;
    if (i < NN) { deg[i] = 1.0f; cnt[i] = 0; }   // self-loop weight 1 pre-added
}

__global__ void edge_deg_cnt(const int* __restrict__ ei, const float* __restrict__ ea,
                             float* __restrict__ deg, int* __restrict__ cnt) {
    int e = blockIdx.x * 256 + threadIdx.x;
    if (e >= NE) return;
    int dst = ei[NE + e];
    atomicAdd(&deg[dst], ea[e]);
    atomicAdd(&cnt[dst], 1);
}

__global__ void compute_dinv(const float* __restrict__ deg, float* __restrict__ dinv) {
    int i = blockIdx.x * 256 + threadIdx.x;
    if (i < NN) { float d = deg[i]; dinv[i] = d > 0.f ? rsqrtf(d) : 0.f; }
}

__global__ void scan_kernel(const int* __restrict__ cnt, int* __restrict__ row_ptr,
                            int* __restrict__ cursor) {
    __shared__ int ssum[256];
    int t = threadIdx.x;
    const int chunk = (NN + 255) / 256;
    int beg = t * chunk;
    int end = beg + chunk; if (end > NN) end = NN;
    int s = 0;
    for (int i = beg; i < end; ++i) s += cnt[i];
    ssum[t] = s;
    __syncthreads();
    if (t == 0) {
        int run = 0;
        for (int i = 0; i < 256; ++i) { int v = ssum[i]; ssum[i] = run; run += v; }
    }
    __syncthreads();
    int run = ssum[t];
    for (int i = beg; i < end; ++i) {
        row_ptr[i] = run; cursor[i] = run; run += cnt[i];
    }
    if (t == 255) row_ptr[NN] = run;
}

__global__ void edge_scatter(const int* __restrict__ ei, const float* __restrict__ ea,
                             const float* __restrict__ dinv, int* __restrict__ cursor,
                             int* __restrict__ col, float* __restrict__ val) {
    int e = blockIdx.x * 256 + threadIdx.x;
    if (e >= NE) return;
    int s = ei[e];
    int d = ei[NE + e];
    int pos = atomicAdd(&cursor[d], 1);
    col[pos] = s;
    val[pos] = dinv[s] * ea[e] * dinv[d];
}

// ---------------------------------------------------------------------------
// Aggregation: one WAVE per node, lane owns 4 feature dims (float4).
// 4-edge unroll => 4 dwordx4 gathers in flight per iteration.
// Optionally writes a bf16 copy into Gbf (stride 768, pre-offset to col block).
// ---------------------------------------------------------------------------
__global__ __launch_bounds__(256) void agg_kernel(
        const float* __restrict__ Gin,
        float* __restrict__ Gout,            // fp32 out [*,256] or nullptr
        __bf16* __restrict__ Gbf,            // bf16 out (stride DOUT) or nullptr
        const float* __restrict__ Rin, float* __restrict__ Rout,
        const int* __restrict__ rowp, const int* __restrict__ colv,
        const float* __restrict__ val, const float* __restrict__ dinv) {
    int node = blockIdx.x * 4 + (threadIdx.x >> 6);
    if (node >= NN) return;
    int lane = threadIdx.x & 63;
    const float* gbase = Gin + (size_t)(lane * 4);
    int beg = rowp[node], end = rowp[node + 1];
    float ax = 0.f, ay = 0.f, az = 0.f, aw = 0.f;
    float racc = 0.f;
    int k = beg;
    for (; k + 4 <= end; k += 4) {
        int   c0 = colv[k],   c1 = colv[k+1], c2 = colv[k+2], c3 = colv[k+3];
        float v0 = val[k],    v1 = val[k+1],  v2 = val[k+2],  v3 = val[k+3];
        float4 g0 = *(const float4*)(gbase + (size_t)c0 * DIN);
        float4 g1 = *(const float4*)(gbase + (size_t)c1 * DIN);
        float4 g2 = *(const float4*)(gbase + (size_t)c2 * DIN);
        float4 g3 = *(const float4*)(gbase + (size_t)c3 * DIN);
        ax += v0 * g0.x; ay += v0 * g0.y; az += v0 * g0.z; aw += v0 * g0.w;
        ax += v1 * g1.x; ay += v1 * g1.y; az += v1 * g1.z; aw += v1 * g1.w;
        ax += v2 * g2.x; ay += v2 * g2.y; az += v2 * g2.z; aw += v2 * g2.w;
        ax += v3 * g3.x; ay += v3 * g3.y; az += v3 * g3.z; aw += v3 * g3.w;
        if (Rout && lane == 0) {
            racc += v0 * (Rin ? Rin[c0] : 1.f) + v1 * (Rin ? Rin[c1] : 1.f)
                  + v2 * (Rin ? Rin[c2] : 1.f) + v3 * (Rin ? Rin[c3] : 1.f);
        }
    }
    for (; k < end; ++k) {
        int c = colv[k]; float v = val[k];
        float4 g = *(const float4*)(gbase + (size_t)c * DIN);
        ax += v * g.x; ay += v * g.y; az += v * g.z; aw += v * g.w;
        if (Rout && lane == 0) racc += v * (Rin ? Rin[c] : 1.f);
    }
    float dv = dinv[node], sv = dv * dv;
    float4 gs = *(const float4*)(gbase + (size_t)node * DIN);
    ax += sv * gs.x; ay += sv * gs.y; az += sv * gs.z; aw += sv * gs.w;
    if (Gout) {
        float4 o = make_float4(ax, ay, az, aw);
        *(float4*)(Gout + (size_t)node * DIN + lane * 4) = o;
    }
    if (Gbf) {
        bf16x4 h;
        h[0] = (__bf16)ax; h[1] = (__bf16)ay; h[2] = (__bf16)az; h[3] = (__bf16)aw;
        *(bf16x4*)(Gbf + (size_t)node * DOUT + lane * 4) = h;
    }
    if (Rout && lane == 0) {
        racc += sv * (Rin ? Rin[node] : 1.f);
        Rout[node] = racc;
    }
}

// ---------------------------------------------------------------------------
// Small dense helpers (weight-side precompute)
// ---------------------------------------------------------------------------
__global__ void sgemm_small(const float* __restrict__ A, const float* __restrict__ B,
                            float* __restrict__ C, int M, int N, int K) {
    int idx = blockIdx.x * blockDim.x + threadIdx.x;
    if (idx >= M * N) return;
    int i = idx / N, j = idx - i * N;
    float s = 0.f;
    for (int k = 0; k < K; ++k) s += A[i * K + k] * B[(size_t)k * N + j];
    C[idx] = s;
}

__global__ void vecmat(const float* __restrict__ v, const float* __restrict__ B,
                       float* __restrict__ out, int K, int N, int ldb, int accum) {
    int j = blockIdx.x * blockDim.x + threadIdx.x;
    if (j >= N) return;
    float s = 0.f;
    for (int k = 0; k < K; ++k) s += v[k] * B[(size_t)k * ldb + j];
    if (accum) out[j] += s; else out[j] = s;
}

__global__ void vadd(float* __restrict__ out, const float* __restrict__ b, int N) {
    int j = blockIdx.x * blockDim.x + threadIdx.x;
    if (j < N) out[j] += b[j];
}

// transpose + convert Mcat[k][n] fp32 -> Bt[n][k] bf16
__global__ void convert_Mt(const float* __restrict__ Mc, __bf16* __restrict__ Bt) {
    int idx = blockIdx.x * 256 + threadIdx.x;
    if (idx >= DOUT * DOUT) return;
    int n = idx / DOUT, k = idx - n * DOUT;
    Bt[idx] = (__bf16)Mc[(size_t)k * DOUT + n];
}

// ---------------------------------------------------------------------------
// MFMA GEMM: C[M,768] = A[M,768](bf16) @ B[768,768](bf16, given as Bt[n][k])
//            + rank-1 epilogue (c0 + R1 u1 + R2 u2 + R3 u3), fp32 out.
// 128x128 block tile, 4 waves, each 64x64 via 4x4 of mfma_f32_16x16x32_bf16.
// global_load_lds width-16 staging; XOR-swizzled 16B chunks for conflict-free
// ds_read_b128 (phys_chunk = (quad + (row>>1)) & 3).
// ---------------------------------------------------------------------------
__device__ inline void g2lds16(const void* g, void* l) {
    __builtin_amdgcn_global_load_lds(
        (__attribute__((address_space(1))) void*)g,
        (__attribute__((address_space(3))) void*)l, 16, 0, 0);
}

__global__ __launch_bounds__(256) void gemm_mfma(
        const __bf16* __restrict__ A,   // [NPAD][768]
        const __bf16* __restrict__ Bt,  // [768][768], Bt[n][k]
        float* __restrict__ C, int M,
        const float* __restrict__ R1, const float* __restrict__ R2,
        const float* __restrict__ R3,
        const float* __restrict__ u1, const float* __restrict__ u2,
        const float* __restrict__ u3, const float* __restrict__ c0) {
    __shared__ __bf16 As[128 * 32];
    __shared__ __bf16 Bs[128 * 32];
    const int tid  = threadIdx.x;
    const int wid  = tid >> 6;
    const int lane = tid & 63;
    const int bm = blockIdx.y * 128;
    const int bn = blockIdx.x * 128;
    const int wm = (wid >> 1) * 64;
    const int wn = (wid & 1) * 64;
    const int l15  = lane & 15;
    const int quad = lane >> 4;

    f32x4 acc[4][4] = {};

    // staging: lane -> row (l>>2) within 16-row group, 16B chunk (l&3).
    const int srow_in_grp = lane >> 2;       // 0..15
    const int schunk      = lane & 3;        // physical chunk this lane fills

    for (int k0 = 0; k0 < DOUT; k0 += 32) {
#pragma unroll
        for (int q = 0; q < 2; ++q) {
            int row = wid * 32 + q * 16 + srow_in_grp;           // 0..127 in tile
            int gchunk = (schunk - ((row >> 1) & 3)) & 3;         // global k-chunk
            const __bf16* ga = A  + (size_t)(bm + row) * DOUT + k0 + gchunk * 8;
            const __bf16* gb = Bt + (size_t)(bn + row) * DOUT + k0 + gchunk * 8;
            g2lds16(ga, As + (size_t)(wid * 32 + q * 16) * 32);
            g2lds16(gb, Bs + (size_t)(wid * 32 + q * 16) * 32);
        }
        __syncthreads();
        bf16x8 af[4], bfr[4];
#pragma unroll
        for (int i = 0; i < 4; ++i) {
            int ra = wm + i * 16 + l15;
            int pa = (quad + ((ra >> 1) & 3)) & 3;
            af[i] = *(const bf16x8*)(As + (size_t)ra * 32 + pa * 8);
            int rb = wn + i * 16 + l15;
            int pb = (quad + ((rb >> 1) & 3)) & 3;
            bfr[i] = *(const bf16x8*)(Bs + (size_t)rb * 32 + pb * 8);
        }
#pragma unroll
        for (int mi = 0; mi < 4; ++mi)
#pragma unroll
            for (int ni = 0; ni < 4; ++ni)
                acc[mi][ni] = __builtin_amdgcn_mfma_f32_16x16x32_bf16(
                    af[mi], bfr[ni], acc[mi][ni], 0, 0, 0);
        __syncthreads();
    }

    // epilogue: per-column constants hoisted
    float e0[4], e1[4], e2[4], e3[4];
#pragma unroll
    for (int ni = 0; ni < 4; ++ni) {
        int gc = bn + wn + ni * 16 + l15;
        e0[ni] = c0[gc]; e1[ni] = u1[gc]; e2[ni] = u2[gc]; e3[ni] = u3[gc];
    }
#pragma unroll
    for (int mi = 0; mi < 4; ++mi) {
#pragma unroll
        for (int r = 0; r < 4; ++r) {
            int gr = bm + wm + mi * 16 + quad * 4 + r;
            if (gr >= M) continue;
            float r1 = R1[gr], r2 = R2[gr], r3 = R3[gr];
#pragma unroll
            for (int ni = 0; ni < 4; ++ni) {
                int gc = bn + wn + ni * 16 + l15;
                C[(size_t)gr * DOUT + gc] =
                    acc[mi][ni][r] + e0[ni] + r1 * e1[ni] + r2 * e2[ni] + r3 * e3[ni];
            }
        }
    }
}

// ---------------------------------------------------------------------------
// Fused LayerNorm + exact GELU, in-place. One block per row.
// ---------------------------------------------------------------------------
__global__ __launch_bounds__(256) void ln_gelu_kernel(float* __restrict__ out,
        const float* __restrict__ gamma, const float* __restrict__ beta) {
    int row = blockIdx.x;
    int t = threadIdx.x;
    float* p = out + (size_t)row * DOUT;
    float x0 = p[t], x1 = p[t + 256], x2 = p[t + 512];
    float s = x0 + x1 + x2;
    float s2 = x0 * x0 + x1 * x1 + x2 * x2;
    __shared__ float red[8];
    int wave = t >> 6, lane = t & 63;
#pragma unroll
    for (int m = 1; m < 64; m <<= 1) {
        s += __shfl_xor(s, m);
        s2 += __shfl_xor(s2, m);
    }
    if (lane == 0) { red[wave] = s; red[4 + wave] = s2; }
    __syncthreads();
    float S = red[0] + red[1] + red[2] + red[3];
    float S2 = red[4] + red[5] + red[6] + red[7];
    float mu = S * (1.f / 768.f);
    float var = S2 * (1.f / 768.f) - mu * mu;
    float inv = rsqrtf(var + 1e-5f);
    const float kk = 0.70710678118654752f;
#pragma unroll
    for (int i = 0; i < 3; ++i) {
        int c = t + 256 * i;
        float x = (i == 0) ? x0 : (i == 1) ? x1 : x2;
        float y = (x - mu) * inv * gamma[c] + beta[c];
        p[c] = 0.5f * y * (1.f + erff(y * kk));
    }
}

// ---------------------------------------------------------------------------
// Launch
// ---------------------------------------------------------------------------
extern "C" void kernel_launch(void* const* d_in, const int* in_sizes, int n_in,
                              void* d_out, int out_size, void* d_ws, size_t ws_size,
                              hipStream_t stream) {
    const float* x     = (const float*)d_in[0];
    const int*   ei    = (const int*)d_in[1];
    const float* ea    = (const float*)d_in[2];
    const float* W1    = (const float*)d_in[3];
    const float* b1    = (const float*)d_in[4];
    const float* W2    = (const float*)d_in[5];
    const float* b2    = (const float*)d_in[6];
    const float* W3    = (const float*)d_in[7];
    const float* b3    = (const float*)d_in[8];
    const float* Wp    = (const float*)d_in[9];
    const float* bp    = (const float*)d_in[10];
    const float* gamma = (const float*)d_in[11];
    const float* beta  = (const float*)d_in[12];
    float* out = (float*)d_out;

    char* w = (char*)d_ws;
    auto alloc = [&](size_t bytes) -> void* {
        void* p = (void*)w;
        w += (bytes + 255) & ~(size_t)255;
        return p;
    };
    __bf16* Gbf  = (__bf16*)alloc((size_t)NPAD * DOUT * 2);  // 77 MB (A for GEMM)
    float* Ga    = (float*)alloc((size_t)NN * DIN * 4);      // 51 MB
    float* Gb    = (float*)alloc((size_t)NN * DIN * 4);      // 51 MB
    int*   col    = (int*)alloc((size_t)NE * 4);
    float* val    = (float*)alloc((size_t)NE * 4);
    float* deg    = (float*)alloc((size_t)NN * 4);
    float* dinv   = (float*)alloc((size_t)NN * 4);
    int*   cnt    = (int*)alloc((size_t)NN * 4);
    int*   rowp   = (int*)alloc((size_t)(NN + 1) * 4);
    int*   cursor = (int*)alloc((size_t)NN * 4);
    float* R1     = (float*)alloc((size_t)NN * 4);
    float* R2     = (float*)alloc((size_t)NN * 4);
    float* R3     = (float*)alloc((size_t)NN * 4);
    float* W2sq   = (float*)alloc(256 * 256 * 4);
    float* W3_2   = (float*)alloc(256 * 256 * 4);
    float* W3_4   = (float*)alloc(256 * 256 * 4);
    float* Mcat   = (float*)alloc(768 * 768 * 4);
    __bf16* Mtbf  = (__bf16*)alloc(768 * 768 * 2);
    float* bw2    = (float*)alloc(256 * 4);
    float* bw3a   = (float*)alloc(256 * 4);
    float* bw3b   = (float*)alloc(256 * 4);
    float* bw3c   = (float*)alloc(256 * 4);
    float* u1     = (float*)alloc(768 * 4);
    float* u2     = (float*)alloc(768 * 4);
    float* u3     = (float*)alloc(768 * 4);
    float* c0     = (float*)alloc(768 * 4);

    const int nb_n = (NN + 255) / 256;
    const int nb_e = (NE + 255) / 256;

    // degree + CSR
    init_deg_cnt<<<nb_n, 256, 0, stream>>>(deg, cnt);
    edge_deg_cnt<<<nb_e, 256, 0, stream>>>(ei, ea, deg, cnt);
    compute_dinv<<<nb_n, 256, 0, stream>>>(deg, dinv);
    scan_kernel<<<1, 256, 0, stream>>>(cnt, rowp, cursor);
    edge_scatter<<<nb_e, 256, 0, stream>>>(ei, ea, dinv, cursor, col, val);

    // weight-side precompute (Mcat = blockdiag(W1, W2^2, W3^4) @ Wp blocks)
    sgemm_small<<<(256 * 256 + 255) / 256, 256, 0, stream>>>(W2, W2, W2sq, 256, 256, 256);
    sgemm_small<<<(256 * 256 + 255) / 256, 256, 0, stream>>>(W3, W3, W3_2, 256, 256, 256);
    sgemm_small<<<(256 * 256 + 255) / 256, 256, 0, stream>>>(W3_2, W3_2, W3_4, 256, 256, 256);
    sgemm_small<<<(256 * 768 + 255) / 256, 256, 0, stream>>>(W1, Wp, Mcat, 256, 768, 256);
    sgemm_small<<<(256 * 768 + 255) / 256, 256, 0, stream>>>(W2sq, Wp + 256 * 768, Mcat + 256 * 768, 256, 768, 256);
    sgemm_small<<<(256 * 768 + 255) / 256, 256, 0, stream>>>(W3_4, Wp + 512 * 768, Mcat + 512 * 768, 256, 768, 256);
    convert_Mt<<<(768 * 768 + 255) / 256, 256, 0, stream>>>(Mcat, Mtbf);
    // bias vectors: b W^k
    vecmat<<<1, 256, 0, stream>>>(b2, W2, bw2, 256, 256, 256, 0);
    vecmat<<<1, 256, 0, stream>>>(b3, W3, bw3a, 256, 256, 256, 0);
    vecmat<<<1, 256, 0, stream>>>(bw3a, W3, bw3b, 256, 256, 256, 0);
    vecmat<<<1, 256, 0, stream>>>(bw3b, W3, bw3c, 256, 256, 256, 0);
    vecmat<<<3, 256, 0, stream>>>(bw2, Wp + 256 * 768, u1, 256, 768, 768, 0);
    vecmat<<<3, 256, 0, stream>>>(bw3a, Wp + 512 * 768, u1, 256, 768, 768, 1);
    vecmat<<<3, 256, 0, stream>>>(bw3b, Wp + 512 * 768, u2, 256, 768, 768, 0);
    vecmat<<<3, 256, 0, stream>>>(bw3c, Wp + 512 * 768, u3, 256, 768, 768, 0);
    vecmat<<<3, 256, 0, stream>>>(b1, Wp, c0, 256, 768, 768, 0);
    vecmat<<<3, 256, 0, stream>>>(b2, Wp + 256 * 768, c0, 256, 768, 768, 1);
    vecmat<<<3, 256, 0, stream>>>(b3, Wp + 512 * 768, c0, 256, 768, 768, 1);
    vadd<<<3, 256, 0, stream>>>(c0, bp, 768);

    // shared aggregation chain: G1=Ax, G2=A G1, G3=A G2, G4=A G3 (+ R chain)
    const int nb_a = (NN + 3) / 4;
    agg_kernel<<<nb_a, 256, 0, stream>>>(x,  Ga, Gbf + 0,   nullptr, R1, rowp, col, val, dinv);
    agg_kernel<<<nb_a, 256, 0, stream>>>(Ga, Gb, Gbf + 256, R1,      R2, rowp, col, val, dinv);
    agg_kernel<<<nb_a, 256, 0, stream>>>(Gb, Ga, nullptr,   R2,      R3, rowp, col, val, dinv);
    agg_kernel<<<nb_a, 256, 0, stream>>>(Ga, nullptr, Gbf + 512, nullptr, nullptr, rowp, col, val, dinv);

    // fused projection GEMM (bf16 MFMA) + bias epilogue
    dim3 grid(DOUT / 128, (NN + 127) / 128);
    gemm_mfma<<<grid, 256, 0, stream>>>(Gbf, Mtbf, out, NN, R1, R2, R3, u1, u2, u3, c0);

    // LayerNorm + exact GELU in-place
    ln_gelu_kernel<<<NN, 256, 0, stream>>>(out, gamma, beta);
}

// Round 3
// 984.486 us; speedup vs baseline: 2.8757x; 2.1025x over previous
//
#include <hip/hip_runtime.h>
#include <math.h>

#define NN 50000        // nodes
#define NE 800000       // edges
#define DIN 256
#define DOUT 768
#define NPAD 50176      // NN padded to multiple of 128 for GEMM tile staging

typedef _Float16 half8 __attribute__((ext_vector_type(8)));
typedef _Float16 half4 __attribute__((ext_vector_type(4)));
typedef float    f32x4 __attribute__((ext_vector_type(4)));

// ---------------------------------------------------------------------------
// Degree / CSR construction
// ---------------------------------------------------------------------------
__global__ void init_deg_cnt(float* __restrict__ deg, int* __restrict__ cnt) {
    int i = blockIdx.x * 256 + threadIdx.x;
    if (i < NN) { deg[i] = 1.0f; cnt[i] = 0; }   // self-loop weight 1 pre-added
}

__global__ void edge_deg_cnt(const int* __restrict__ ei, const float* __restrict__ ea,
                             float* __restrict__ deg, int* __restrict__ cnt) {
    int e = blockIdx.x * 256 + threadIdx.x;
    if (e >= NE) return;
    int dst = ei[NE + e];
    atomicAdd(&deg[dst], ea[e]);
    atomicAdd(&cnt[dst], 1);
}

__global__ void compute_dinv(const float* __restrict__ deg, float* __restrict__ dinv) {
    int i = blockIdx.x * 256 + threadIdx.x;
    if (i < NN) { float d = deg[i]; dinv[i] = d > 0.f ? rsqrtf(d) : 0.f; }
}

// 1024-thread single-block scan of cnt -> row_ptr (+ cursor copy)
__global__ __launch_bounds__(1024) void scan_kernel(
        const int* __restrict__ cnt, int* __restrict__ row_ptr,
        int* __restrict__ cursor) {
    __shared__ int ssum[1024];
    int t = threadIdx.x;
    const int chunk = (NN + 1023) / 1024;   // 49
    int beg = t * chunk;
    int end = beg + chunk; if (end > NN) end = NN;
    int s = 0;
    for (int i = beg; i < end; ++i) s += cnt[i];
    ssum[t] = s;
    __syncthreads();
    if (t == 0) {
        int run = 0;
        for (int i = 0; i < 1024; ++i) { int v = ssum[i]; ssum[i] = run; run += v; }
    }
    __syncthreads();
    int run = ssum[t];
    for (int i = beg; i < end; ++i) {
        row_ptr[i] = run; cursor[i] = run; run += cnt[i];
    }
    if (t == 0) row_ptr[NN] = NE;
}

__global__ void edge_scatter(const int* __restrict__ ei, const float* __restrict__ ea,
                             const float* __restrict__ dinv, int* __restrict__ cursor,
                             int* __restrict__ col, float* __restrict__ val) {
    int e = blockIdx.x * 256 + threadIdx.x;
    if (e >= NE) return;
    int s = ei[e];
    int d = ei[NE + e];
    int pos = atomicAdd(&cursor[d], 1);
    col[pos] = s;
    val[pos] = dinv[s] * ea[e] * dinv[d];
}

// convert x fp32 -> fp16 (4 elems/thread)
__global__ void x2h_kernel(const float* __restrict__ x, _Float16* __restrict__ Xh) {
    int i = blockIdx.x * 256 + threadIdx.x;
    if (i >= NN * DIN / 4) return;
    float4 v = ((const float4*)x)[i];
    half4 h; h[0] = (_Float16)v.x; h[1] = (_Float16)v.y;
    h[2] = (_Float16)v.z; h[3] = (_Float16)v.w;
    ((half4*)Xh)[i] = h;
}

// ---------------------------------------------------------------------------
// Aggregation, fp16 in / fp16 out, fp32 accumulate. One WAVE per node.
// Row = 256 fp16 = 512 B = 32 lanes x 16 B. Half-wave sub=lane>>5 takes
// alternate edges; 2x unroll => 4 edges in flight per wave iteration.
// ---------------------------------------------------------------------------
__global__ __launch_bounds__(256) void agg_kernel(
        const _Float16* __restrict__ Gin, int sIn,
        _Float16* __restrict__ Gout, int sOut,
        const float* __restrict__ Rin, float* __restrict__ Rout,
        const int* __restrict__ rowp, const int* __restrict__ colv,
        const float* __restrict__ val, const float* __restrict__ dinv) {
    int node = blockIdx.x * 4 + (threadIdx.x >> 6);
    if (node >= NN) return;
    int lane = threadIdx.x & 63;
    int sub = lane >> 5, l32 = lane & 31;
    const _Float16* gb = Gin + l32 * 8;
    float acc[8] = {0.f, 0.f, 0.f, 0.f, 0.f, 0.f, 0.f, 0.f};
    float racc = 0.f;
    int beg = rowp[node], end = rowp[node + 1];
    int k = beg;
    for (; k + 4 <= end; k += 4) {
        int e0 = k + sub, e1 = k + 2 + sub;
        int   c0 = colv[e0], c1 = colv[e1];
        float v0 = val[e0],  v1 = val[e1];
        half8 g0 = *(const half8*)(gb + (size_t)c0 * sIn);
        half8 g1 = *(const half8*)(gb + (size_t)c1 * sIn);
#pragma unroll
        for (int j = 0; j < 8; ++j)
            acc[j] += v0 * (float)g0[j] + v1 * (float)g1[j];
        if (l32 == 0)
            racc += v0 * (Rin ? Rin[c0] : 1.f) + v1 * (Rin ? Rin[c1] : 1.f);
    }
    for (; k < end; k += 2) {
        int e = k + sub;
        if (e < end) {
            int c = colv[e]; float v = val[e];
            half8 g = *(const half8*)(gb + (size_t)c * sIn);
#pragma unroll
            for (int j = 0; j < 8; ++j) acc[j] += v * (float)g[j];
            if (l32 == 0) racc += v * (Rin ? Rin[c] : 1.f);
        }
    }
    // combine the two half-wave partial sums
#pragma unroll
    for (int j = 0; j < 8; ++j) acc[j] += __shfl_xor(acc[j], 32);
    racc += __shfl_xor(racc, 32);
    float dv = dinv[node], sv = dv * dv;
    half8 gs = *(const half8*)(gb + (size_t)node * sIn);
#pragma unroll
    for (int j = 0; j < 8; ++j) acc[j] += sv * (float)gs[j];
    if (sub == 0) {
        half8 o;
#pragma unroll
        for (int j = 0; j < 8; ++j) o[j] = (_Float16)acc[j];
        *(half8*)(Gout + (size_t)node * sOut + l32 * 8) = o;
    }
    if (Rout && lane == 0)
        Rout[node] = racc + sv * (Rin ? Rin[node] : 1.f);
}

// ---------------------------------------------------------------------------
// Weight-side precompute, consolidated into 4 launches.
// wp1: W2sq = W2@W2, W3_2 = W3@W3, bw2 = b2@W2, bw3a = b3@W3    (514 blocks)
// wp2: W3_4 = W3_2@W3_2, bw3b = bw3a@W3                          (257 blocks)
// wp3: Mt (fp16, transposed) = blockdiag(W1,W2sq,W3_4)@Wp blocks, bw3c (769)
// wp4: u1, u2, u3, c0                                            (12 blocks)
// ---------------------------------------------------------------------------
__global__ __launch_bounds__(256) void wp1(
        const float* __restrict__ W2, const float* __restrict__ W3,
        const float* __restrict__ b2, const float* __restrict__ b3,
        float* __restrict__ W2sq, float* __restrict__ W3_2,
        float* __restrict__ bw2, float* __restrict__ bw3a) {
    int b = blockIdx.x, j = threadIdx.x;
    const float* A; const float* B; float* C;
    if (b < 256)      { A = W2 + b * 256;         B = W2; C = W2sq + b * 256; }
    else if (b < 512) { A = W3 + (b - 256) * 256; B = W3; C = W3_2 + (b - 256) * 256; }
    else if (b == 512){ A = b2;                   B = W2; C = bw2; }
    else              { A = b3;                   B = W3; C = bw3a; }
    float s = 0.f;
#pragma unroll 8
    for (int k = 0; k < 256; ++k) s += A[k] * B[k * 256 + j];
    C[j] = s;
}

__global__ __launch_bounds__(256) void wp2(
        const float* __restrict__ W3_2, const float* __restrict__ W3,
        const float* __restrict__ bw3a,
        float* __restrict__ W3_4, float* __restrict__ bw3b) {
    int b = blockIdx.x, j = threadIdx.x;
    const float* A; const float* B; float* C;
    if (b < 256) { A = W3_2 + b * 256; B = W3_2; C = W3_4 + b * 256; }
    else         { A = bw3a;           B = W3;   C = bw3b; }
    float s = 0.f;
#pragma unroll 8
    for (int k = 0; k < 256; ++k) s += A[k] * B[k * 256 + j];
    C[j] = s;
}

__global__ __launch_bounds__(256) void wp3(
        const float* __restrict__ W1, const float* __restrict__ W2sq,
        const float* __restrict__ W3_4, const float* __restrict__ Wp,
        const float* __restrict__ W3, const float* __restrict__ bw3b,
        _Float16* __restrict__ Mt, float* __restrict__ bw3c) {
    int b = blockIdx.x, j = threadIdx.x;
    if (b == 768) {   // bw3c = bw3b @ W3
        float s = 0.f;
#pragma unroll 8
        for (int k = 0; k < 256; ++k) s += bw3b[k] * W3[k * 256 + j];
        bw3c[j] = s;
        return;
    }
    int kk = b;                       // output row of Mcat = column of Mt
    int blk = kk >> 8;                // 0,1,2
    const float* A = (blk == 0) ? (W1 + kk * 256)
                   : (blk == 1) ? (W2sq + (kk - 256) * 256)
                                : (W3_4 + (kk - 512) * 256);
    const float* B = Wp + (size_t)(blk * 256) * 768;
    float s0 = 0.f, s1 = 0.f, s2 = 0.f;
#pragma unroll 4
    for (int m = 0; m < 256; ++m) {
        float a = A[m];
        const float* br = B + (size_t)m * 768;
        s0 += a * br[j]; s1 += a * br[j + 256]; s2 += a * br[j + 512];
    }
    // Mt[n][k] = Mcat[k][n]
    Mt[(size_t)j * 768 + kk]         = (_Float16)s0;
    Mt[(size_t)(j + 256) * 768 + kk] = (_Float16)s1;
    Mt[(size_t)(j + 512) * 768 + kk] = (_Float16)s2;
}

__global__ __launch_bounds__(256) void wp4(
        const float* __restrict__ Wp,
        const float* __restrict__ b1, const float* __restrict__ b2,
        const float* __restrict__ b3, const float* __restrict__ bp,
        const float* __restrict__ bw2, const float* __restrict__ bw3a,
        const float* __restrict__ bw3b, const float* __restrict__ bw3c,
        float* __restrict__ u1, float* __restrict__ u2,
        float* __restrict__ u3, float* __restrict__ c0) {
    int vec = blockIdx.x / 3, chunk = blockIdx.x % 3;
    int j = chunk * 256 + threadIdx.x;
    const float* P1 = Wp;
    const float* P2 = Wp + (size_t)256 * 768;
    const float* P3 = Wp + (size_t)512 * 768;
    float s = 0.f;
    if (vec == 0) {        // u1 = bw2@P2 + bw3a@P3
#pragma unroll 8
        for (int k = 0; k < 256; ++k) s += bw2[k] * P2[(size_t)k * 768 + j];
#pragma unroll 8
        for (int k = 0; k < 256; ++k) s += bw3a[k] * P3[(size_t)k * 768 + j];
        u1[j] = s;
    } else if (vec == 1) { // u2 = bw3b@P3
#pragma unroll 8
        for (int k = 0; k < 256; ++k) s += bw3b[k] * P3[(size_t)k * 768 + j];
        u2[j] = s;
    } else if (vec == 2) { // u3 = bw3c@P3
#pragma unroll 8
        for (int k = 0; k < 256; ++k) s += bw3c[k] * P3[(size_t)k * 768 + j];
        u3[j] = s;
    } else {               // c0 = b1@P1 + b2@P2 + b3@P3 + bp
#pragma unroll 8
        for (int k = 0; k < 256; ++k) s += b1[k] * P1[(size_t)k * 768 + j];
#pragma unroll 8
        for (int k = 0; k < 256; ++k) s += b2[k] * P2[(size_t)k * 768 + j];
#pragma unroll 8
        for (int k = 0; k < 256; ++k) s += b3[k] * P3[(size_t)k * 768 + j];
        c0[j] = s + bp[j];
    }
}

// ---------------------------------------------------------------------------
// MFMA GEMM: C[M,768] = A[M,768](fp16) @ B (fp16, given as Bt[n][k])
//            + rank-1 epilogue (c0 + R1 u1 + R2 u2 + R3 u3), fp32 out.
// 128x128 tile, 4 waves x (4x4 of mfma_f32_16x16x32_f16), global_load_lds
// width-16 staging, XOR-swizzled 16B chunks for conflict-free ds_read_b128.
// ---------------------------------------------------------------------------
__device__ inline void g2lds16(const void* g, void* l) {
    __builtin_amdgcn_global_load_lds(
        (__attribute__((address_space(1))) void*)g,
        (__attribute__((address_space(3))) void*)l, 16, 0, 0);
}

__global__ __launch_bounds__(256) void gemm_mfma(
        const _Float16* __restrict__ A,   // [NPAD][768]
        const _Float16* __restrict__ Bt,  // [768][768], Bt[n][k]
        float* __restrict__ C, int M,
        const float* __restrict__ R1, const float* __restrict__ R2,
        const float* __restrict__ R3,
        const float* __restrict__ u1, const float* __restrict__ u2,
        const float* __restrict__ u3, const float* __restrict__ c0) {
    __shared__ _Float16 As[128 * 32];
    __shared__ _Float16 Bs[128 * 32];
    const int tid  = threadIdx.x;
    const int wid  = tid >> 6;
    const int lane = tid & 63;
    const int bm = blockIdx.y * 128;
    const int bn = blockIdx.x * 128;
    const int wm = (wid >> 1) * 64;
    const int wn = (wid & 1) * 64;
    const int l15  = lane & 15;
    const int quad = lane >> 4;

    f32x4 acc[4][4] = {};

    const int srow_in_grp = lane >> 2;       // 0..15
    const int schunk      = lane & 3;        // physical 16B chunk this lane fills

    for (int k0 = 0; k0 < DOUT; k0 += 32) {
#pragma unroll
        for (int q = 0; q < 2; ++q) {
            int row = wid * 32 + q * 16 + srow_in_grp;            // 0..127
            int gchunk = (schunk - ((row >> 1) & 3)) & 3;          // global k-chunk
            const _Float16* ga = A  + (size_t)(bm + row) * DOUT + k0 + gchunk * 8;
            const _Float16* gb = Bt + (size_t)(bn + row) * DOUT + k0 + gchunk * 8;
            g2lds16(ga, As + (size_t)(wid * 32 + q * 16) * 32);
            g2lds16(gb, Bs + (size_t)(wid * 32 + q * 16) * 32);
        }
        __syncthreads();
        half8 af[4], bfr[4];
#pragma unroll
        for (int i = 0; i < 4; ++i) {
            int ra = wm + i * 16 + l15;
            int pa = (quad + ((ra >> 1) & 3)) & 3;
            af[i] = *(const half8*)(As + (size_t)ra * 32 + pa * 8);
            int rb = wn + i * 16 + l15;
            int pb = (quad + ((rb >> 1) & 3)) & 3;
            bfr[i] = *(const half8*)(Bs + (size_t)rb * 32 + pb * 8);
        }
#pragma unroll
        for (int mi = 0; mi < 4; ++mi)
#pragma unroll
            for (int ni = 0; ni < 4; ++ni)
                acc[mi][ni] = __builtin_amdgcn_mfma_f32_16x16x32_f16(
                    af[mi], bfr[ni], acc[mi][ni], 0, 0, 0);
        __syncthreads();
    }

    float e0[4], e1[4], e2[4], e3[4];
#pragma unroll
    for (int ni = 0; ni < 4; ++ni) {
        int gc = bn + wn + ni * 16 + l15;
        e0[ni] = c0[gc]; e1[ni] = u1[gc]; e2[ni] = u2[gc]; e3[ni] = u3[gc];
    }
#pragma unroll
    for (int mi = 0; mi < 4; ++mi) {
#pragma unroll
        for (int r = 0; r < 4; ++r) {
            int gr = bm + wm + mi * 16 + quad * 4 + r;
            if (gr >= M) continue;
            float r1 = R1[gr], r2 = R2[gr], r3 = R3[gr];
#pragma unroll
            for (int ni = 0; ni < 4; ++ni) {
                int gc = bn + wn + ni * 16 + l15;
                C[(size_t)gr * DOUT + gc] =
                    acc[mi][ni][r] + e0[ni] + r1 * e1[ni] + r2 * e2[ni] + r3 * e3[ni];
            }
        }
    }
}

// ---------------------------------------------------------------------------
// Fused LayerNorm + exact GELU, in-place. One block per row.
// ---------------------------------------------------------------------------
__global__ __launch_bounds__(256) void ln_gelu_kernel(float* __restrict__ out,
        const float* __restrict__ gamma, const float* __restrict__ beta) {
    int row = blockIdx.x;
    int t = threadIdx.x;
    float* p = out + (size_t)row * DOUT;
    float x0 = p[t], x1 = p[t + 256], x2 = p[t + 512];
    float s = x0 + x1 + x2;
    float s2 = x0 * x0 + x1 * x1 + x2 * x2;
    __shared__ float red[8];
    int wave = t >> 6, lane = t & 63;
#pragma unroll
    for (int m = 1; m < 64; m <<= 1) {
        s += __shfl_xor(s, m);
        s2 += __shfl_xor(s2, m);
    }
    if (lane == 0) { red[wave] = s; red[4 + wave] = s2; }
    __syncthreads();
    float S = red[0] + red[1] + red[2] + red[3];
    float S2 = red[4] + red[5] + red[6] + red[7];
    float mu = S * (1.f / 768.f);
    float var = S2 * (1.f / 768.f) - mu * mu;
    float inv = rsqrtf(var + 1e-5f);
    const float kk = 0.70710678118654752f;
#pragma unroll
    for (int i = 0; i < 3; ++i) {
        int c = t + 256 * i;
        float x = (i == 0) ? x0 : (i == 1) ? x1 : x2;
        float y = (x - mu) * inv * gamma[c] + beta[c];
        p[c] = 0.5f * y * (1.f + erff(y * kk));
    }
}

// ---------------------------------------------------------------------------
// Launch
// ---------------------------------------------------------------------------
extern "C" void kernel_launch(void* const* d_in, const int* in_sizes, int n_in,
                              void* d_out, int out_size, void* d_ws, size_t ws_size,
                              hipStream_t stream) {
    const float* x     = (const float*)d_in[0];
    const int*   ei    = (const int*)d_in[1];
    const float* ea    = (const float*)d_in[2];
    const float* W1    = (const float*)d_in[3];
    const float* b1    = (const float*)d_in[4];
    const float* W2    = (const float*)d_in[5];
    const float* b2    = (const float*)d_in[6];
    const float* W3    = (const float*)d_in[7];
    const float* b3    = (const float*)d_in[8];
    const float* Wp    = (const float*)d_in[9];
    const float* bp    = (const float*)d_in[10];
    const float* gamma = (const float*)d_in[11];
    const float* beta  = (const float*)d_in[12];
    float* out = (float*)d_out;

    char* w = (char*)d_ws;
    auto alloc = [&](size_t bytes) -> void* {
        void* p = (void*)w;
        w += (bytes + 255) & ~(size_t)255;
        return p;
    };
    _Float16* Acat = (_Float16*)alloc((size_t)NPAD * DOUT * 2);  // 77 MB  G1|G2|G4
    _Float16* Xh   = (_Float16*)alloc((size_t)NN * DIN * 2);     // 25 MB
    _Float16* G3h  = (_Float16*)alloc((size_t)NN * DIN * 2);     // 25 MB
    _Float16* Mt   = (_Float16*)alloc((size_t)DOUT * DOUT * 2);  // 1.2 MB
    int*   col    = (int*)alloc((size_t)NE * 4);
    float* val    = (float*)alloc((size_t)NE * 4);
    float* deg    = (float*)alloc((size_t)NN * 4);
    float* dinv   = (float*)alloc((size_t)NN * 4);
    int*   cnt    = (int*)alloc((size_t)NN * 4);
    int*   rowp   = (int*)alloc((size_t)(NN + 1) * 4);
    int*   cursor = (int*)alloc((size_t)NN * 4);
    float* R1     = (float*)alloc((size_t)NN * 4);
    float* R2     = (float*)alloc((size_t)NN * 4);
    float* R3     = (float*)alloc((size_t)NN * 4);
    float* W2sq   = (float*)alloc(256 * 256 * 4);
    float* W3_2   = (float*)alloc(256 * 256 * 4);
    float* W3_4   = (float*)alloc(256 * 256 * 4);
    float* bw2    = (float*)alloc(256 * 4);
    float* bw3a   = (float*)alloc(256 * 4);
    float* bw3b   = (float*)alloc(256 * 4);
    float* bw3c   = (float*)alloc(256 * 4);
    float* u1     = (float*)alloc(768 * 4);
    float* u2     = (float*)alloc(768 * 4);
    float* u3     = (float*)alloc(768 * 4);
    float* c0     = (float*)alloc(768 * 4);

    const int nb_n = (NN + 255) / 256;
    const int nb_e = (NE + 255) / 256;

    // degree + CSR
    init_deg_cnt<<<nb_n, 256, 0, stream>>>(deg, cnt);
    edge_deg_cnt<<<nb_e, 256, 0, stream>>>(ei, ea, deg, cnt);
    compute_dinv<<<nb_n, 256, 0, stream>>>(deg, dinv);
    scan_kernel<<<1, 1024, 0, stream>>>(cnt, rowp, cursor);
    edge_scatter<<<nb_e, 256, 0, stream>>>(ei, ea, dinv, cursor, col, val);

    // x -> fp16
    x2h_kernel<<<(NN * DIN / 4 + 255) / 256, 256, 0, stream>>>(x, Xh);

    // weight-side precompute, 4 launches
    wp1<<<514, 256, 0, stream>>>(W2, W3, b2, b3, W2sq, W3_2, bw2, bw3a);
    wp2<<<257, 256, 0, stream>>>(W3_2, W3, bw3a, W3_4, bw3b);
    wp3<<<769, 256, 0, stream>>>(W1, W2sq, W3_4, Wp, W3, bw3b, Mt, bw3c);
    wp4<<<12, 256, 0, stream>>>(Wp, b1, b2, b3, bp, bw2, bw3a, bw3b, bw3c,
                                u1, u2, u3, c0);

    // shared aggregation chain: G1=Ax, G2=A G1, G3=A G2, G4=A G3 (+ R chain)
    const int nb_a = (NN + 3) / 4;
    agg_kernel<<<nb_a, 256, 0, stream>>>(Xh, DIN,          Acat + 0,   DOUT, nullptr, R1, rowp, col, val, dinv);
    agg_kernel<<<nb_a, 256, 0, stream>>>(Acat + 0,   DOUT, Acat + 256, DOUT, R1,      R2, rowp, col, val, dinv);
    agg_kernel<<<nb_a, 256, 0, stream>>>(Acat + 256, DOUT, G3h,        DIN,  R2,      R3, rowp, col, val, dinv);
    agg_kernel<<<nb_a, 256, 0, stream>>>(G3h,        DIN,  Acat + 512, DOUT, nullptr, nullptr, rowp, col, val, dinv);

    // fused projection GEMM (fp16 MFMA) + bias epilogue
    dim3 grid(DOUT / 128, (NN + 127) / 128);
    gemm_mfma<<<grid, 256, 0, stream>>>(Acat, Mt, out, NN, R1, R2, R3, u1, u2, u3, c0);

    // LayerNorm + exact GELU in-place
    ln_gelu_kernel<<<NN, 256, 0, stream>>>(out, gamma, beta);
}